// Round 1
// baseline (163.319 us; speedup 1.0000x reference)
//
#include <hip/hip_runtime.h>
#include <math.h>

#define N_LEAVES 65536
#define WAVES 24
#define WC 2048
#define KSPLITS 3
#define S 128
#define CTOT (N_LEAVES + WAVES * WC)   // 114688
#define G 2048
#define E_ITERS 50
#define EPS 1e-30f

// ---------------------------------------------------------------------------
// setup: scalar DTL rates, extinction fixed point (e stays uniform across S,
// so it is a scalar iteration), survival denominator. Also zeroes d_out.
// ---------------------------------------------------------------------------
__global__ void setup_kernel(const float* __restrict__ theta,
                             float* __restrict__ consts,
                             float* __restrict__ out) {
    float D = exp2f(theta[0]);
    float L = exp2f(theta[1]);
    float T = exp2f(theta[2]);
    float norm = D + L + T + 1.0f;
    float e = L / norm;
    for (int i = 0; i < E_ITERS; ++i)
        e = (L + D * e * e + T * e * e) / norm;   // mean(e) == e (uniform)
    float denom = 1.0f + D * e + T * e;
    consts[0] = D;
    consts[1] = L;
    consts[2] = T;
    consts[3] = 1.0f + D;          // (1+D)
    consts[4] = T / 127.0f;        // T/(S-1)
    consts[5] = denom;
    out[0] = 0.0f;
}

// ---------------------------------------------------------------------------
// init: zero P[C][S] (float4 stores), zero ls[C], leaf one-hots inline
// (each float4 chunk of a leaf row checks whether its species lands in it —
// no second pass, no race).
// ---------------------------------------------------------------------------
__global__ __launch_bounds__(256) void init_kernel(float4* __restrict__ P4,
                                                   float* __restrict__ ls,
                                                   const int* __restrict__ leaf_species) {
    const long NP4 = (long)CTOT * S / 4;   // 3,670,016
    long idx = (long)blockIdx.x * blockDim.x + threadIdx.x;
    long stride = (long)gridDim.x * blockDim.x;
    for (long i = idx; i < NP4; i += stride) {
        float4 v = make_float4(0.f, 0.f, 0.f, 0.f);
        long row = i >> 5;                 // 32 float4 per row (S=128)
        int col4 = (int)(i & 31) << 2;
        if (row < N_LEAVES) {
            int sp = leaf_species[row];
            if (sp >= col4 && sp < col4 + 4)
                ((float*)&v)[sp - col4] = 1.0f;
        }
        P4[i] = v;
    }
    for (long i = idx; i < CTOT; i += stride)
        ls[i] = 0.0f;
}

// ---------------------------------------------------------------------------
// one wave: 2048 clades, 1 wavefront (64 lanes) per clade, lane owns 2
// species (float2). Gathers of rows inside the CURRENT wave's output range
// are masked to zero (reference reads the pre-wave carry, which is zero).
// ---------------------------------------------------------------------------
__global__ __launch_bounds__(256) void wave_kernel(
    const float* __restrict__ logw, const int* __restrict__ left,
    const int* __restrict__ right, float* __restrict__ P,
    float* __restrict__ ls, const float* __restrict__ consts, int k) {
    const int lane = threadIdx.x & 63;
    const int wv = threadIdx.x >> 6;
    const int c = blockIdx.x * 4 + wv;          // clade within wave, [0, WC)
    const int row_id = N_LEAVES + k * WC + c;
    const int base = (k * WC + c) * KSPLITS;

    const float onepD = consts[3];
    const float T127 = consts[4];
    const float denom = consts[5];

    const int lo = N_LEAVES + k * WC;
    const int hi = lo + WC;

    // CCP split softmax (K=3)
    float w0, w1, w2;
    {
        float l0 = logw[base + 0], l1 = logw[base + 1], l2 = logw[base + 2];
        float m = fmaxf(l0, fmaxf(l1, l2));
        float e0 = expf(l0 - m), e1 = expf(l1 - m), e2 = expf(l2 - m);
        float inv = 1.0f / (e0 + e1 + e2);
        w0 = e0 * inv; w1 = e1 * inv; w2 = e2 * inv;
    }
    const float wj[KSPLITS] = {w0, w1, w2};

    float2 pl[KSPLITS], pr[KSPLITS];
    float sl[KSPLITS], sr[KSPLITS];
#pragma unroll
    for (int j = 0; j < KSPLITS; ++j) {
        int li = left[base + j];
        int ri = right[base + j];
        float2 a = make_float2(0.f, 0.f), b = make_float2(0.f, 0.f);
        if (li < lo || li >= hi)
            a = *(const float2*)&P[(long)li * S + 2 * lane];
        if (ri < lo || ri >= hi)
            b = *(const float2*)&P[(long)ri * S + 2 * lane];
        pl[j] = a; pr[j] = b;
    }
#pragma unroll
    for (int j = 0; j < KSPLITS; ++j) {
        float s1 = pl[j].x + pl[j].y;
        float s2 = pr[j].x + pr[j].y;
#pragma unroll
        for (int d = 1; d < 64; d <<= 1) {
            s1 += __shfl_xor(s1, d);
            s2 += __shfl_xor(s2, d);
        }
        sl[j] = s1; sr[j] = s2;
    }
    float v0 = 0.f, v1 = 0.f;
#pragma unroll
    for (int j = 0; j < KSPLITS; ++j) {
        v0 += wj[j] * (onepD * pl[j].x * pr[j].x +
                       T127 * (pl[j].x * (sr[j] - pr[j].x) + pr[j].x * (sl[j] - pl[j].x)));
        v1 += wj[j] * (onepD * pl[j].y * pr[j].y +
                       T127 * (pl[j].y * (sr[j] - pr[j].y) + pr[j].y * (sl[j] - pl[j].y)));
    }
    v0 /= denom;
    v1 /= denom;

    float m = fmaxf(v0, v1);
#pragma unroll
    for (int d = 1; d < 64; d <<= 1)
        m = fmaxf(m, __shfl_xor(m, d));
    float safe = fmaxf(m, EPS);

    float2 outv = make_float2(v0 / safe, v1 / safe);
    *(float2*)&P[(long)row_id * S + 2 * lane] = outv;
    if (lane == 0)
        ls[row_id] = logf(safe);
}

// ---------------------------------------------------------------------------
// final: per-family ll = log(sum_s P[root]) + ls[root]; NLL = -sum.
// One wavefront per family, grid-stride over families, one atomicAdd/wave.
// ---------------------------------------------------------------------------
__global__ __launch_bounds__(256) void final_kernel(
    const int* __restrict__ root_ids, const float* __restrict__ P,
    const float* __restrict__ ls, float* __restrict__ out) {
    const int lane = threadIdx.x & 63;
    const int wid = (int)((blockIdx.x * blockDim.x + threadIdx.x) >> 6);
    const int nw = (int)((gridDim.x * blockDim.x) >> 6);
    float acc = 0.f;
    for (int g = wid; g < G; g += nw) {
        int r = root_ids[g];
        float2 p = *(const float2*)&P[(long)r * S + 2 * lane];
        float s = p.x + p.y;
#pragma unroll
        for (int d = 1; d < 64; d <<= 1)
            s += __shfl_xor(s, d);
        if (lane == 0)
            acc += logf(s + EPS) + ls[r];
    }
    if (lane == 0)
        atomicAdd(out, -acc);
}

// ---------------------------------------------------------------------------
extern "C" void kernel_launch(void* const* d_in, const int* in_sizes, int n_in,
                              void* d_out, int out_size, void* d_ws, size_t ws_size,
                              hipStream_t stream) {
    const float* theta        = (const float*)d_in[0];
    const float* logw         = (const float*)d_in[1];
    const int*   left         = (const int*)d_in[2];
    const int*   right        = (const int*)d_in[3];
    const int*   leaf_species = (const int*)d_in[4];
    const int*   root_ids     = (const int*)d_in[5];
    float* out = (float*)d_out;

    char* ws = (char*)d_ws;
    float* consts = (float*)ws;                                  // 256 B region
    float* P      = (float*)(ws + 256);                          // C*S*4 = 58,720,256 B
    float* ls     = (float*)(ws + 256 + (size_t)CTOT * S * 4);   // C*4 = 458,752 B

    setup_kernel<<<1, 1, 0, stream>>>(theta, consts, out);
    init_kernel<<<2048, 256, 0, stream>>>((float4*)P, ls, leaf_species);
    for (int k = 0; k < WAVES; ++k)
        wave_kernel<<<WC / 4, 256, 0, stream>>>(logw, left, right, P, ls, consts, k);
    final_kernel<<<128, 256, 0, stream>>>(root_ids, P, ls, out);
}